// Round 11
// baseline (254.678 us; speedup 1.0000x reference)
//
#include <hip/hip_runtime.h>
#include <cstdint>
#include <cstddef>

#define B_TOK 4096
#define DIM   512
#define HID   1024
#define NEXP  16
#define NSLOT 4

typedef __bf16 bf16x8 __attribute__((ext_vector_type(8)));
typedef float  f32x4  __attribute__((ext_vector_type(4)));
typedef unsigned short ushort8 __attribute__((ext_vector_type(8)));
typedef unsigned short ushort4v __attribute__((ext_vector_type(4)));

static __device__ __forceinline__ unsigned short f2bf(float f) {
    union { float f; unsigned u; } v; v.f = f;
    unsigned r = v.u + 0x7FFFu + ((v.u >> 16) & 1u);   // round-to-nearest-even
    return (unsigned short)(r >> 16);
}
static __device__ __forceinline__ float bf2f(unsigned short u) {
    union { unsigned u; float f; } v; v.u = (unsigned)u << 16; return v.f;
}

// async global->LDS, 16B per lane, dest = wave-uniform base + lane*16
static __device__ __forceinline__ void gl_lds16(const unsigned short* g, unsigned short* l) {
    __builtin_amdgcn_global_load_lds(
        (const __attribute__((address_space(1))) unsigned int*)(const void*)g,
        (__attribute__((address_space(3))) unsigned int*)(void*)l, 16, 0, 0);
}

// swizzled fragment read, 128B rows (64 shorts): byte = row*128 + ((ks*2) ^ ((row&7)<<4))
static __device__ __forceinline__ bf16x8 fragRD(const unsigned short* s, int row, int ks) {
    int byte = row * 128 + ((ks * 2) ^ ((row & 7) << 4));
    return *(const bf16x8*)((const char*)s + byte);
}
// swizzled fragment read, 64B rows (32 shorts): byte = row*64 + ((ks*2) ^ ((row&3)<<4))
static __device__ __forceinline__ bf16x8 fragRD32(const unsigned short* s, int row, int ks) {
    int byte = row * 64 + ((ks * 2) ^ ((row & 3) << 4));
    return *(const bf16x8*)((const char*)s + byte);
}

// ---------------- ws layout (bytes) ----------------
#define LOGITS_OFF 0x0000000u  // B*E fp32               (256 KB)
#define LTOK_OFF   0x0100000u  // E*B int                (256 KB)
#define LGATE_OFF  0x0140000u  // E*B fp32               (256 KB)
#define CTRL_OFF   0x0180000u  // [0..15]=cnt [16..31]=imp [32..47]=bases [48]=np [64..]=pairs
#define PMAP_OFF   0x01A0000u  // B*4 int (64 KB)        token -> (e<<12)|pos
#define XBF_OFF    0x0200000u  // B*D bf16               (4 MB)
#define W1T_OFF    0x0600000u  // E*H*D bf16 [E][H][D]   (16 MB) -- REUSED as yslot by ffn2
#define W2T_OFF    0x1600000u  // E*D*H bf16 [E][D][H]   (16 MB)
#define H_OFF      0x2600000u  // 16384*1024 bf16        (32 MB)  end 0x4600000
#define YS_OFF     W1T_OFF     // yslot: 16384*512 bf16  (16 MB)  [w1t dead after ffn1]

// ---------------- kernel 0 (merged): logits, x->bf16 + counters, w1 cvt+transpose ----------------
// grid 4096: [0,1024) logits, [1024,2048) cvtx, [2048,4096) w1 tiles.  (w2 cvt in k_ffn1)
__global__ __launch_bounds__(256) void k_init(
        int* cnt, float* imp,
        const float* __restrict__ x, unsigned short* __restrict__ xbf,
        const float* __restrict__ w1, unsigned short* __restrict__ w1t,
        const float* __restrict__ gx, const float* __restrict__ wg,
        float* __restrict__ logits) {
    __shared__ unsigned short T[64][74];
    const int bid = blockIdx.x;
    const int t = threadIdx.x;
    if (bid < 1024) {
        int row = bid * 4 + (t >> 6);
        int l = t & 63;
        int e = l & 15;
        int c = l >> 4;
        const float* xr = gx + (size_t)row * DIM + c * 128;
        const float* wc = wg + (size_t)(c * 128) * NEXP + e;
        float s = 0.0f;
        #pragma unroll 8
        for (int d = 0; d < 128; d += 4) {
            float4 v = *(const float4*)(xr + d);
            s += v.x * wc[(d + 0) * NEXP] + v.y * wc[(d + 1) * NEXP]
               + v.z * wc[(d + 2) * NEXP] + v.w * wc[(d + 3) * NEXP];
        }
        s += __shfl_xor(s, 16);
        s += __shfl_xor(s, 32);
        if (l < NEXP) logits[row * NEXP + l] = s;
        return;
    }
    if (bid < 2048) {
        int i = (bid - 1024) * 256 + t;        // 262144 = B*D/8 exactly
        const float4* s = (const float4*)(x + (size_t)i * 8);
        float4 a = s[0], b = s[1];
        ushort8 v = { f2bf(a.x), f2bf(a.y), f2bf(a.z), f2bf(a.w),
                      f2bf(b.x), f2bf(b.y), f2bf(b.z), f2bf(b.w) };
        *(ushort8*)(xbf + (size_t)i * 8) = v;
        if (bid == 1024 && t < NEXP) { cnt[t] = 0; imp[t] = 0.0f; }
        return;
    }
    // w1 convert+transpose: [E][512][1024] f32 -> [E][1024][512] bf16
    const int idx = bid - 2048;
    const int ktiles = DIM >> 6;           // 8
    const int e   = idx >> 7;              // 128 tiles per expert
    const int rem = idx & 127;
    const int k0 = (rem % ktiles) * 64;
    const int n0 = (rem / ktiles) * 64;
    const int kr = t >> 4, n4 = (t & 15) * 4;
    #pragma unroll
    for (int it = 0; it < 4; it++) {
        int k = kr + it * 16;
        float4 v = *(const float4*)(w1 + ((size_t)e * DIM + k0 + k) * HID + n0 + n4);
        T[n4 + 0][k] = f2bf(v.x);
        T[n4 + 1][k] = f2bf(v.y);
        T[n4 + 2][k] = f2bf(v.z);
        T[n4 + 3][k] = f2bf(v.w);
    }
    __syncthreads();
    const int nn = t >> 3, k8 = (t & 7) * 8;
    #pragma unroll
    for (int rep = 0; rep < 2; rep++) {
        int n = nn + rep * 32;
        ushort8 o;
        #pragma unroll
        for (int i = 0; i < 8; i++) o[i] = T[n][k8 + i];
        *(ushort8*)(w1t + ((size_t)e * HID + n0 + n) * DIM + k0 + k8) = o;
    }
}

// ---------------- kernel 2: top-4 + softmax + two-level routing scatter + posmap ----------------
__global__ __launch_bounds__(64) void k_route(const float* __restrict__ logits,
                        int* __restrict__ cnt, float* __restrict__ imp,
                        int* __restrict__ ltok, float* __restrict__ lgate,
                        int* __restrict__ posmap) {
    __shared__ int   lcnt[NEXP];
    __shared__ float limp[NEXP];
    __shared__ int   lbase[NEXP];
    const int t = threadIdx.x;
    if (t < NEXP) { lcnt[t] = 0; limp[t] = 0.0f; }
    __syncthreads();

    const int b = blockIdx.x * 64 + t;
    const float4* lp = (const float4*)(logits + (size_t)b * NEXP);
    float4 q0 = lp[0], q1 = lp[1], q2 = lp[2], q3 = lp[3];
    float lg[NEXP] = { q0.x, q0.y, q0.z, q0.w, q1.x, q1.y, q1.z, q1.w,
                       q2.x, q2.y, q2.z, q2.w, q3.x, q3.y, q3.z, q3.w };

    int idx[NSLOT]; float val[NSLOT];
    unsigned used = 0;
    #pragma unroll
    for (int j = 0; j < NSLOT; j++) {
        float bv = -1e30f; int bi = 0;
        #pragma unroll
        for (int i = 0; i < NEXP; i++) {
            bool ok = !((used >> i) & 1u);
            if (ok && lg[i] > bv) { bv = lg[i]; bi = i; }
        }
        idx[j] = bi; val[j] = bv; used |= (1u << bi);
    }
    float m = val[0];
    float ex[NSLOT]; float sum = 0.0f;
    #pragma unroll
    for (int j = 0; j < NSLOT; j++) { ex[j] = __expf(val[j] - m); sum += ex[j]; }
    float inv = 1.0f / sum;

    int   lpos[NSLOT];
    float gv[NSLOT];
    #pragma unroll
    for (int j = 0; j < NSLOT; j++) {
        gv[j] = ex[j] * inv;
        lpos[j] = atomicAdd(&lcnt[idx[j]], 1);
        atomicAdd(&limp[idx[j]], gv[j]);
    }
    __syncthreads();
    if (t < NEXP) {
        lbase[t] = atomicAdd(&cnt[t], lcnt[t]);
        atomicAdd(&imp[t], limp[t]);
    }
    __syncthreads();
    #pragma unroll
    for (int j = 0; j < NSLOT; j++) {
        int e = idx[j];
        int p = lbase[e] + lpos[j];
        ltok[e * B_TOK + p]  = b;
        lgate[e * B_TOK + p] = gv[j];
        posmap[b * NSLOT + j] = (e << 12) | p;
    }
}

// ---------------- kernel 3: prefix bases + loss + work-list (one wave) ----------------
__global__ void k_prep(int* __restrict__ ctrl, float* __restrict__ out_loss) {
    const int* cnt = ctrl;
    const float* imp = (const float*)(ctrl + 16);
    int* bases = ctrl + 32;
    int* np    = ctrl + 48;
    int* pairs = ctrl + 64;
    int l = threadIdx.x;
    if (l >= 16) return;
    int base = 0, poff = 0;
    #pragma unroll
    for (int j = 0; j < 16; j++) {
        int cj = cnt[j];
        base += (j < l) ? cj : 0;
        poff += (j < l) ? ((cj + 127) >> 7) : 0;
    }
    bases[l] = base;
    int c = cnt[l];
    int ntile = (c + 127) >> 7;
    for (int i = 0; i < ntile; i++) pairs[poff + i] = (l << 16) | i;
    if (l == 15) *np = poff + ntile;

    float cf = (float)c, im = imp[l];
    float sc = cf, si = im;
    #pragma unroll
    for (int m = 8; m >= 1; m >>= 1) { sc += __shfl_xor(sc, m, 16); si += __shfl_xor(si, m, 16); }
    float ml = sc / 16.0f, mi = si / 16.0f;
    float dc = cf - ml, di = im - mi;
    float vc = dc * dc, vi = di * di;
    #pragma unroll
    for (int m = 8; m >= 1; m >>= 1) { vc += __shfl_xor(vc, m, 16); vi += __shfl_xor(vi, m, 16); }
    vc /= 15.0f; vi /= 15.0f;
    if (l == 0) *out_loss = vi / (mi * mi + 1e-10f) + vc / (ml * ml + 1e-10f);
}

// ---------------- pass 1: h = relu(X_e @ w1t^T + b1)  tile 128x128, BK=32, 6 blocks/CU ----------------
// ONE-GENERATION fix: 1088 GEMM blocks > 768 slots (3/CU) forced the busiest slot to run 2
// blocks serially (~21us) -- that quantization, not the inner loop, is ffn1's deficit vs ffn2
// (ffn2: 544 blocks/768 slots = 1 gen, 860 TF = structure ceiling). BK=32 cuts LDS to ~17KB
// -> launch_bounds(256,6) -> 1536 slots >= 1088 -> one generation. Same MFMA count per block
// (16 steps x 16 MFMA/wave). Epilogue in two 64-row half-passes (St=16KB).
// Grid 3328: [0,1280) ffn1 work-list; [1280,3328) w2 cvt+transpose (independent, overlapped).
__global__ __launch_bounds__(256, 6) void k_ffn1(
        const unsigned short* __restrict__ xbf, const unsigned short* __restrict__ w1t,
        const float* __restrict__ b1, const int* __restrict__ ctrl,
        const int* __restrict__ ltok, unsigned short* __restrict__ hbuf,
        const float* __restrict__ w2, unsigned short* __restrict__ w2t) {
    __shared__ __align__(16) unsigned short Sh[2][128 * 32];   // As | Bs (8KB each); St=16KB; cvt T alias
    __shared__ int toks[128];

    const int orig = blockIdx.x;
    const int tid = threadIdx.x;

    if (orig >= 1280) {
        // ---- w2 convert+transpose: [E][1024][512] f32 -> [E][512][1024] bf16 ----
        unsigned short (*T)[74] = (unsigned short (*)[74])&Sh[0][0];   // 9.25KB alias over 16KB
        const int idx = orig - 1280;           // 0..2047
        const int ktiles = HID >> 6;           // 16
        const int e   = idx >> 7;
        const int rem = idx & 127;
        const int k0 = (rem % ktiles) * 64;
        const int n0 = (rem / ktiles) * 64;
        const int kr = tid >> 4, n4 = (tid & 15) * 4;
        #pragma unroll
        for (int it = 0; it < 4; it++) {
            int k = kr + it * 16;
            float4 v = *(const float4*)(w2 + ((size_t)e * HID + k0 + k) * DIM + n0 + n4);
            T[n4 + 0][k] = f2bf(v.x);
            T[n4 + 1][k] = f2bf(v.y);
            T[n4 + 2][k] = f2bf(v.z);
            T[n4 + 3][k] = f2bf(v.w);
        }
        __syncthreads();
        const int nn = tid >> 3, k8 = (tid & 7) * 8;
        #pragma unroll
        for (int rep = 0; rep < 2; rep++) {
            int n = nn + rep * 32;
            ushort8 o;
            #pragma unroll
            for (int i = 0; i < 8; i++) o[i] = T[n][k8 + i];
            *(ushort8*)(w2t + ((size_t)e * DIM + n0 + n) * HID + k0 + k8) = o;
        }
        return;
    }

    // ---- ffn1 proper ----
    // XCD-chunked bijective remap: 1280 = 8 * 160
    const int wgid = (orig & 7) * 160 + (orig >> 3);
    const int pi = wgid >> 3, nt = wgid & 7;
    if (pi >= ctrl[48]) return;
    const int pr = ctrl[64 + pi];
    const int e  = pr >> 16;
    const int mt = pr & 0xffff;
    const int n_e = ctrl[e];
    const int base = ctrl[32 + e];
    const int row0 = mt * 128;

    unsigned short* As = &Sh[0][0];
    unsigned short* Bs = &Sh[1][0];

    const int lane = tid & 63, wv = tid >> 6;
    const int wm = wv >> 1, wn = wv & 1;
    const int lr = lane & 15, lq = lane >> 4;

    if (tid < 128) toks[tid] = ltok[e * B_TOK + min(row0 + tid, n_e - 1)];
    __syncthreads();

    // BK=32 staging: 128 rows x 32 shorts per operand = 8KB = 8 x 1KB chunks.
    // id s in [0,512): row r = s>>2, chunk-in-row cq = s&3, source k-chunk kc = cq ^ (r&3).
    const unsigned short* a_src[2];
    const unsigned short* b_src[2];
    #pragma unroll
    for (int c = 0; c < 2; c++) {
        int s = (wv * 2 + c) * 64 + lane;
        int r = s >> 2;
        int kc = (s & 3) ^ (r & 3);
        a_src[c] = xbf + (size_t)toks[r] * DIM + kc * 8;
        b_src[c] = w1t + ((size_t)(e * HID + nt * 128 + r)) * DIM + kc * 8;
    }

    f32x4 acc[4][4];
    #pragma unroll
    for (int m = 0; m < 4; m++)
        #pragma unroll
        for (int n = 0; n < 4; n++) acc[m][n] = (f32x4){0.f, 0.f, 0.f, 0.f};

    for (int kt = 0; kt < DIM; kt += 32) {
        #pragma unroll
        for (int c = 0; c < 2; c++) {
            gl_lds16(a_src[c] + kt, &As[(wv * 2 + c) * 512]);
            gl_lds16(b_src[c] + kt, &Bs[(wv * 2 + c) * 512]);
        }
        __syncthreads();
        {
            bf16x8 af[4], bfr[4];
            #pragma unroll
            for (int i = 0; i < 4; i++) {
                af[i]  = fragRD32(As, wm * 64 + i * 16 + lr, lq * 8);
                bfr[i] = fragRD32(Bs, wn * 64 + i * 16 + lr, lq * 8);
            }
            #pragma unroll
            for (int i = 0; i < 4; i++)
                #pragma unroll
                for (int j = 0; j < 4; j++)
                    acc[i][j] = __builtin_amdgcn_mfma_f32_16x16x32_bf16(af[i], bfr[j], acc[i][j], 0, 0, 0);
        }
        __syncthreads();
    }

    // epilogue: two 64-row half-passes through St (16KB = all of Sh), swizzled rows of 256B
    unsigned short* St = &Sh[0][0];
    #pragma unroll
    for (int h = 0; h < 2; h++) {
        if (wm == h) {
            #pragma unroll
            for (int j = 0; j < 4; j++) {
                int col = wn * 64 + j * 16 + lr;
                float bias = b1[e * HID + nt * 128 + col];
                #pragma unroll
                for (int i = 0; i < 4; i++) {
                    #pragma unroll
                    for (int q = 0; q < 4; q++) {
                        int row = i * 16 + lq * 4 + q;          // 0..63 within half
                        float v = acc[i][j][q] + bias;
                        v = v > 0.0f ? v : 0.0f;
                        int byte = row * 256 + ((col * 2) ^ ((row & 7) << 4));
                        *(unsigned short*)((char*)St + byte) = f2bf(v);
                    }
                }
            }
        }
        __syncthreads();
        // store 64 rows x 128 cols = 8192 shorts: 256 thr x 8 shorts x 4 iters
        #pragma unroll
        for (int r8 = 0; r8 < 4; r8++) {
            int idx = r8 * 2048 + tid * 8;
            int row = idx >> 7;
            int colw = idx & 127;
            int pos = row0 + h * 64 + row;
            if (pos < n_e) {
                int byte = row * 256 + ((colw * 2) ^ ((row & 7) << 4));
                ushort8 o = *(const ushort8*)((const char*)St + byte);
                *(ushort8*)(hbuf + (size_t)(base + pos) * HID + nt * 128 + colw) = o;
            }
        }
        __syncthreads();
    }
}

// ---------------- pass 2: yslot[slot] = gate*(H_e @ w2t^T + b2)  tile 128x128 (R7-exact) ----------------
__global__ __launch_bounds__(256, 3) void k_ffn2(
        const unsigned short* __restrict__ hbuf, const unsigned short* __restrict__ w2t,
        const float* __restrict__ b2, const int* __restrict__ ctrl,
        const float* __restrict__ lgate,
        unsigned short* __restrict__ yslot) {
    const int orig = blockIdx.x;
    const int wgid = (orig & 7) * 72 + (orig >> 3);
    const int pi = wgid >> 2, nt = wgid & 3;
    if (pi >= ctrl[48]) return;
    const int pr = ctrl[64 + pi];
    const int e  = pr >> 16;
    const int mt = pr & 0xffff;
    const int n_e = ctrl[e];
    const int base = ctrl[32 + e];
    const int row0 = mt * 128;

    __shared__ __align__(16) unsigned short Sh[2][128 * 64];
    __shared__ float gts[128];
    unsigned short* As = &Sh[0][0];
    unsigned short* Bs = &Sh[1][0];

    const int tid = threadIdx.x;
    const int lane = tid & 63, wv = tid >> 6;
    const int wm = wv >> 1, wn = wv & 1;
    const int lr = lane & 15, lq = lane >> 4;

    if (tid < 128) {
        int p = min(row0 + tid, n_e - 1);
        gts[tid] = lgate[e * B_TOK + p];
    }
    __syncthreads();

    const unsigned short* a_src[4];
    const unsigned short* b_src[4];
    #pragma unroll
    for (int c = 0; c < 4; c++) {
        int s = (wv * 4 + c) * 64 + lane;
        int r = s >> 3;
        int kc = (s & 7) ^ (r & 7);
        a_src[c] = hbuf + (size_t)(base + min(row0 + r, n_e - 1)) * HID + kc * 8;
        b_src[c] = w2t + ((size_t)(e * DIM + nt * 128 + r)) * HID + kc * 8;
    }

    f32x4 acc[4][4];
    #pragma unroll
    for (int m = 0; m < 4; m++)
        #pragma unroll
        for (int n = 0; n < 4; n++) acc[m][n] = (f32x4){0.f, 0.f, 0.f, 0.f};

    for (int kt = 0; kt < HID; kt += 64) {
        #pragma unroll
        for (int c = 0; c < 4; c++) {
            gl_lds16(a_src[c] + kt, &As[(wv * 4 + c) * 512]);
            gl_lds16(b_src[c] + kt, &Bs[(wv * 4 + c) * 512]);
        }
        __syncthreads();
        #pragma unroll
        for (int kk = 0; kk < 64; kk += 32) {
            bf16x8 af[4], bfr[4];
            #pragma unroll
            for (int i = 0; i < 4; i++) {
                af[i]  = fragRD(As, wm * 64 + i * 16 + lr, kk + lq * 8);
                bfr[i] = fragRD(Bs, wn * 64 + i * 16 + lr, kk + lq * 8);
            }
            #pragma unroll
            for (int i = 0; i < 4; i++)
                #pragma unroll
                for (int j = 0; j < 4; j++)
                    acc[i][j] = __builtin_amdgcn_mfma_f32_16x16x32_bf16(af[i], bfr[j], acc[i][j], 0, 0, 0);
        }
        __syncthreads();
    }

    // epilogue phase 1: bias + gate -> Sh (swizzled, row stride 256B)
    unsigned short* St = &Sh[0][0];
    #pragma unroll
    for (int j = 0; j < 4; j++) {
        int col = wn * 64 + j * 16 + lr;
        float bias = b2[e * DIM + nt * 128 + col];
        #pragma unroll
        for (int i = 0; i < 4; i++) {
            #pragma unroll
            for (int q = 0; q < 4; q++) {
                int row = wm * 64 + i * 16 + lq * 4 + q;
                float v = (acc[i][j][q] + bias) * gts[row];
                int byte = row * 256 + ((col * 2) ^ ((row & 7) << 4));
                *(unsigned short*)((char*)St + byte) = f2bf(v);
            }
        }
    }
    __syncthreads();
    // epilogue phase 2: coalesced 16B stores
    #pragma unroll
    for (int r8 = 0; r8 < 8; r8++) {
        int idx = r8 * 2048 + tid * 8;
        int row = idx >> 7;
        int colw = idx & 127;
        int pos = row0 + row;
        if (pos < n_e) {
            int byte = row * 256 + ((colw * 2) ^ ((row & 7) << 4));
            ushort8 o = *(const ushort8*)((const char*)St + byte);
            *(ushort8*)(yslot + (size_t)(base + pos) * DIM + nt * 128 + colw) = o;
        }
    }
}

// ---------------- kernel 5: y[b] = sum_j yslot[slot_j(b)]  (coalesced, no atomics) ----------------
__global__ __launch_bounds__(256) void k_gather(
        const unsigned short* __restrict__ yslot, const int* __restrict__ posmap,
        const int* __restrict__ ctrl, float* __restrict__ y) {
    const int tok = blockIdx.x * 4 + (threadIdx.x >> 6);
    const int c8  = (threadIdx.x & 63) * 8;
    float s[8] = {0.f, 0.f, 0.f, 0.f, 0.f, 0.f, 0.f, 0.f};
    #pragma unroll
    for (int j = 0; j < NSLOT; j++) {
        int pm = posmap[tok * NSLOT + j];
        int e = pm >> 12, p = pm & 4095;
        size_t row = (size_t)(ctrl[32 + e] + p);
        ushort8 v = *(const ushort8*)(yslot + row * DIM + c8);
        #pragma unroll
        for (int q = 0; q < 8; q++) s[q] += bf2f(v[q]);
    }
    float4 o0 = {s[0], s[1], s[2], s[3]};
    float4 o1 = {s[4], s[5], s[6], s[7]};
    *(float4*)(y + (size_t)tok * DIM + c8)     = o0;
    *(float4*)(y + (size_t)tok * DIM + c8 + 4) = o1;
}

// ---------------- host launcher ----------------
extern "C" void kernel_launch(void* const* d_in, const int* in_sizes, int n_in,
                              void* d_out, int out_size, void* d_ws, size_t ws_size,
                              hipStream_t stream) {
    const float* x  = (const float*)d_in[0];
    const float* gx = (const float*)d_in[1];
    const float* wg = (const float*)d_in[2];
    const float* w1 = (const float*)d_in[3];
    const float* b1 = (const float*)d_in[4];
    const float* w2 = (const float*)d_in[5];
    const float* b2 = (const float*)d_in[6];
    float* out = (float*)d_out;

    char* ws = (char*)d_ws;
    float* logits = (float*)(ws + LOGITS_OFF);
    int*   ltok   = (int*)(ws + LTOK_OFF);
    float* lgate  = (float*)(ws + LGATE_OFF);
    int*   ctrl   = (int*)(ws + CTRL_OFF);
    int*   cnt    = ctrl;
    float* imp    = (float*)(ctrl + 16);
    int*   posmap = (int*)(ws + PMAP_OFF);
    unsigned short* xbf   = (unsigned short*)(ws + XBF_OFF);
    unsigned short* w1t   = (unsigned short*)(ws + W1T_OFF);
    unsigned short* w2t   = (unsigned short*)(ws + W2T_OFF);
    unsigned short* hbuf  = (unsigned short*)(ws + H_OFF);
    unsigned short* yslot = (unsigned short*)(ws + YS_OFF);   // aliases w1t (dead after ffn1)

    hipLaunchKernelGGL(k_init, dim3(4096), dim3(256), 0, stream,
                       cnt, imp, x, xbf, w1, w1t, gx, wg, logits);
    hipLaunchKernelGGL(k_route, dim3(B_TOK / 64), dim3(64), 0, stream,
                       logits, cnt, imp, ltok, lgate, posmap);
    hipLaunchKernelGGL(k_prep, dim3(1), dim3(64), 0, stream, ctrl,
                       out + (size_t)B_TOK * DIM);
    hipLaunchKernelGGL(k_ffn1, dim3(3328), dim3(256), 0, stream,
                       xbf, w1t, b1, ctrl, ltok, hbuf, w2, w2t);
    hipLaunchKernelGGL(k_ffn2, dim3(576), dim3(256), 0, stream,
                       hbuf, w2t, b2, ctrl, lgate, yslot);
    hipLaunchKernelGGL(k_gather, dim3(B_TOK / 4), dim3(256), 0, stream,
                       yslot, posmap, ctrl, out);
}

// Round 12
// 91.181 us; speedup vs baseline: 2.7931x; 2.7931x over previous
//
#include <hip/hip_runtime.h>
#include <cstdint>
#include <cstddef>

#define B_TOK 4096
#define DIM   512
#define HID   1024
#define NEXP  16
#define NSLOT 4

typedef __bf16 bf16x8 __attribute__((ext_vector_type(8)));
typedef float  f32x4  __attribute__((ext_vector_type(4)));
typedef unsigned short ushort8 __attribute__((ext_vector_type(8)));
typedef unsigned short ushort4v __attribute__((ext_vector_type(4)));

static __device__ __forceinline__ unsigned short f2bf(float f) {
    union { float f; unsigned u; } v; v.f = f;
    unsigned r = v.u + 0x7FFFu + ((v.u >> 16) & 1u);   // round-to-nearest-even
    return (unsigned short)(r >> 16);
}
static __device__ __forceinline__ float bf2f(unsigned short u) {
    union { unsigned u; float f; } v; v.u = (unsigned)u << 16; return v.f;
}

// async global->LDS, 16B per lane, dest = wave-uniform base + lane*16
static __device__ __forceinline__ void gl_lds16(const unsigned short* g, unsigned short* l) {
    __builtin_amdgcn_global_load_lds(
        (const __attribute__((address_space(1))) unsigned int*)(const void*)g,
        (__attribute__((address_space(3))) unsigned int*)(void*)l, 16, 0, 0);
}

// swizzled fragment read: row stride 128B (64 shorts); byte = row*128 + ((ks*2) ^ ((row&7)<<4))
static __device__ __forceinline__ bf16x8 fragRD(const unsigned short* s, int row, int ks) {
    int byte = row * 128 + ((ks * 2) ^ ((row & 7) << 4));
    return *(const bf16x8*)((const char*)s + byte);
}

// ---------------- ws layout (bytes) ----------------
#define LOGITS_OFF 0x0000000u  // B*E fp32               (256 KB)
#define LTOK_OFF   0x0100000u  // E*B int                (256 KB)
#define LGATE_OFF  0x0140000u  // E*B fp32               (256 KB)
#define CTRL_OFF   0x0180000u  // [0..15]=cnt [16..31]=imp [32..47]=bases [48]=np [64..]=pairs
#define PMAP_OFF   0x01A0000u  // B*4 int (64 KB)        token -> (e<<12)|pos
#define XBF_OFF    0x0200000u  // B*D bf16               (4 MB)
#define W1T_OFF    0x0600000u  // E*H*D bf16 [E][H][D]   (16 MB) -- REUSED as yslot by ffn2
#define W2T_OFF    0x1600000u  // E*D*H bf16 [E][D][H]   (16 MB)
#define H_OFF      0x2600000u  // 16384*1024 bf16        (32 MB)  end 0x4600000
#define YS_OFF     W1T_OFF     // yslot: 16384*512 bf16  (16 MB)  [w1t dead after ffn1]

// ---------------- kernel 0 (merged): logits, x->bf16 + counters, w1 cvt+transpose ----------------
// grid 4096: [0,1024) logits, [1024,2048) cvtx, [2048,4096) w1 tiles.  (w2 cvt in k_ffn1)
__global__ __launch_bounds__(256) void k_init(
        int* cnt, float* imp,
        const float* __restrict__ x, unsigned short* __restrict__ xbf,
        const float* __restrict__ w1, unsigned short* __restrict__ w1t,
        const float* __restrict__ gx, const float* __restrict__ wg,
        float* __restrict__ logits) {
    __shared__ unsigned short T[64][74];
    const int bid = blockIdx.x;
    const int t = threadIdx.x;
    if (bid < 1024) {
        int row = bid * 4 + (t >> 6);
        int l = t & 63;
        int e = l & 15;
        int c = l >> 4;
        const float* xr = gx + (size_t)row * DIM + c * 128;
        const float* wc = wg + (size_t)(c * 128) * NEXP + e;
        float s = 0.0f;
        #pragma unroll 8
        for (int d = 0; d < 128; d += 4) {
            float4 v = *(const float4*)(xr + d);
            s += v.x * wc[(d + 0) * NEXP] + v.y * wc[(d + 1) * NEXP]
               + v.z * wc[(d + 2) * NEXP] + v.w * wc[(d + 3) * NEXP];
        }
        s += __shfl_xor(s, 16);
        s += __shfl_xor(s, 32);
        if (l < NEXP) logits[row * NEXP + l] = s;
        return;
    }
    if (bid < 2048) {
        int i = (bid - 1024) * 256 + t;        // 262144 = B*D/8 exactly
        const float4* s = (const float4*)(x + (size_t)i * 8);
        float4 a = s[0], b = s[1];
        ushort8 v = { f2bf(a.x), f2bf(a.y), f2bf(a.z), f2bf(a.w),
                      f2bf(b.x), f2bf(b.y), f2bf(b.z), f2bf(b.w) };
        *(ushort8*)(xbf + (size_t)i * 8) = v;
        if (bid == 1024 && t < NEXP) { cnt[t] = 0; imp[t] = 0.0f; }
        return;
    }
    // w1 convert+transpose: [E][512][1024] f32 -> [E][1024][512] bf16
    const int idx = bid - 2048;
    const int ktiles = DIM >> 6;           // 8
    const int e   = idx >> 7;              // 128 tiles per expert
    const int rem = idx & 127;
    const int k0 = (rem % ktiles) * 64;
    const int n0 = (rem / ktiles) * 64;
    const int kr = t >> 4, n4 = (t & 15) * 4;
    #pragma unroll
    for (int it = 0; it < 4; it++) {
        int k = kr + it * 16;
        float4 v = *(const float4*)(w1 + ((size_t)e * DIM + k0 + k) * HID + n0 + n4);
        T[n4 + 0][k] = f2bf(v.x);
        T[n4 + 1][k] = f2bf(v.y);
        T[n4 + 2][k] = f2bf(v.z);
        T[n4 + 3][k] = f2bf(v.w);
    }
    __syncthreads();
    const int nn = t >> 3, k8 = (t & 7) * 8;
    #pragma unroll
    for (int rep = 0; rep < 2; rep++) {
        int n = nn + rep * 32;
        ushort8 o;
        #pragma unroll
        for (int i = 0; i < 8; i++) o[i] = T[n][k8 + i];
        *(ushort8*)(w1t + ((size_t)e * HID + n0 + n) * DIM + k0 + k8) = o;
    }
}

// ---------------- kernel 2: top-4 + softmax + two-level routing scatter + posmap ----------------
// 64 blocks x 64 threads: per-wave aggregation, float4 logits loads.
__global__ __launch_bounds__(64) void k_route(const float* __restrict__ logits,
                        int* __restrict__ cnt, float* __restrict__ imp,
                        int* __restrict__ ltok, float* __restrict__ lgate,
                        int* __restrict__ posmap) {
    __shared__ int   lcnt[NEXP];
    __shared__ float limp[NEXP];
    __shared__ int   lbase[NEXP];
    const int t = threadIdx.x;
    if (t < NEXP) { lcnt[t] = 0; limp[t] = 0.0f; }
    __syncthreads();

    const int b = blockIdx.x * 64 + t;
    const float4* lp = (const float4*)(logits + (size_t)b * NEXP);
    float4 q0 = lp[0], q1 = lp[1], q2 = lp[2], q3 = lp[3];
    float lg[NEXP] = { q0.x, q0.y, q0.z, q0.w, q1.x, q1.y, q1.z, q1.w,
                       q2.x, q2.y, q2.z, q2.w, q3.x, q3.y, q3.z, q3.w };

    int idx[NSLOT]; float val[NSLOT];
    unsigned used = 0;
    #pragma unroll
    for (int j = 0; j < NSLOT; j++) {
        float bv = -1e30f; int bi = 0;
        #pragma unroll
        for (int i = 0; i < NEXP; i++) {
            bool ok = !((used >> i) & 1u);
            if (ok && lg[i] > bv) { bv = lg[i]; bi = i; }
        }
        idx[j] = bi; val[j] = bv; used |= (1u << bi);
    }
    float m = val[0];
    float ex[NSLOT]; float sum = 0.0f;
    #pragma unroll
    for (int j = 0; j < NSLOT; j++) { ex[j] = __expf(val[j] - m); sum += ex[j]; }
    float inv = 1.0f / sum;

    int   lpos[NSLOT];
    float gv[NSLOT];
    #pragma unroll
    for (int j = 0; j < NSLOT; j++) {
        gv[j] = ex[j] * inv;
        lpos[j] = atomicAdd(&lcnt[idx[j]], 1);
        atomicAdd(&limp[idx[j]], gv[j]);
    }
    __syncthreads();
    if (t < NEXP) {
        lbase[t] = atomicAdd(&cnt[t], lcnt[t]);
        atomicAdd(&imp[t], limp[t]);
    }
    __syncthreads();
    #pragma unroll
    for (int j = 0; j < NSLOT; j++) {
        int e = idx[j];
        int p = lbase[e] + lpos[j];
        ltok[e * B_TOK + p]  = b;
        lgate[e * B_TOK + p] = gv[j];
        posmap[b * NSLOT + j] = (e << 12) | p;
    }
}

// ---------------- kernel 3: prefix bases + loss + work-list (one wave) ----------------
__global__ void k_prep(int* __restrict__ ctrl, float* __restrict__ out_loss) {
    const int* cnt = ctrl;
    const float* imp = (const float*)(ctrl + 16);
    int* bases = ctrl + 32;
    int* np    = ctrl + 48;
    int* pairs = ctrl + 64;
    int l = threadIdx.x;
    if (l >= 16) return;
    int base = 0, poff = 0;
    #pragma unroll
    for (int j = 0; j < 16; j++) {
        int cj = cnt[j];
        base += (j < l) ? cj : 0;
        poff += (j < l) ? ((cj + 127) >> 7) : 0;
    }
    bases[l] = base;
    int c = cnt[l];
    int ntile = (c + 127) >> 7;
    for (int i = 0; i < ntile; i++) pairs[poff + i] = (l << 16) | i;
    if (l == 15) *np = poff + ntile;

    float cf = (float)c, im = imp[l];
    float sc = cf, si = im;
    #pragma unroll
    for (int m = 8; m >= 1; m >>= 1) { sc += __shfl_xor(sc, m, 16); si += __shfl_xor(si, m, 16); }
    float ml = sc / 16.0f, mi = si / 16.0f;
    float dc = cf - ml, di = im - mi;
    float vc = dc * dc, vi = di * di;
    #pragma unroll
    for (int m = 8; m >= 1; m >>= 1) { vc += __shfl_xor(vc, m, 16); vi += __shfl_xor(vi, m, 16); }
    vc /= 15.0f; vi /= 15.0f;
    if (l == 0) *out_loss = vi / (mi * mi + 1e-10f) + vc / (ml * ml + 1e-10f);
}

// ---------------- pass 1: h = relu(X_e @ w1t^T + b1)  tile 128x128, BK=64 ----------------
// Best-measured configuration (91.7us total). The 128x128/BK=64/3-per-CU point proved a sharp
// local optimum: R0 occupancy-4, R1 128x256, R2/R3 dbuf+vmcnt, R4 balanced map, R9 sorted-A,
// R10 256^2, R11 BK=32 all neutral-or-worse. w2-cvt co-tenant rides ~free in the latency-bound
// GEMM phase (R5/R6 ablation: ~15us standalone -> ~3-5us here).
// Grid 3328: [0,1280) ffn1 work-list; [1280,3328) w2 cvt+transpose (independent, overlapped).
__global__ __launch_bounds__(256, 3) void k_ffn1(
        const unsigned short* __restrict__ xbf, const unsigned short* __restrict__ w1t,
        const float* __restrict__ b1, const int* __restrict__ ctrl,
        const int* __restrict__ ltok, unsigned short* __restrict__ hbuf,
        const float* __restrict__ w2, unsigned short* __restrict__ w2t) {
    __shared__ __align__(16) unsigned short Sh[2][128 * 64];   // As | Bs, reused as out-tile / cvt T
    __shared__ int toks[128];

    const int orig = blockIdx.x;
    const int tid = threadIdx.x;

    if (orig >= 1280) {
        // ---- w2 convert+transpose: [E][1024][512] f32 -> [E][512][1024] bf16 ----
        unsigned short (*T)[74] = (unsigned short (*)[74])&Sh[0][0];   // 9.5KB alias
        const int idx = orig - 1280;           // 0..2047
        const int ktiles = HID >> 6;           // 16
        const int e   = idx >> 7;
        const int rem = idx & 127;
        const int k0 = (rem % ktiles) * 64;
        const int n0 = (rem / ktiles) * 64;
        const int kr = tid >> 4, n4 = (tid & 15) * 4;
        #pragma unroll
        for (int it = 0; it < 4; it++) {
            int k = kr + it * 16;
            float4 v = *(const float4*)(w2 + ((size_t)e * HID + k0 + k) * DIM + n0 + n4);
            T[n4 + 0][k] = f2bf(v.x);
            T[n4 + 1][k] = f2bf(v.y);
            T[n4 + 2][k] = f2bf(v.z);
            T[n4 + 3][k] = f2bf(v.w);
        }
        __syncthreads();
        const int nn = tid >> 3, k8 = (tid & 7) * 8;
        #pragma unroll
        for (int rep = 0; rep < 2; rep++) {
            int n = nn + rep * 32;
            ushort8 o;
            #pragma unroll
            for (int i = 0; i < 8; i++) o[i] = T[n][k8 + i];
            *(ushort8*)(w2t + ((size_t)e * DIM + n0 + n) * HID + k0 + k8) = o;
        }
        return;
    }

    // ---- ffn1 proper ----
    // XCD-chunked bijective remap: 1280 = 8 * 160
    const int wgid = (orig & 7) * 160 + (orig >> 3);
    const int pi = wgid >> 3, nt = wgid & 7;
    if (pi >= ctrl[48]) return;
    const int pr = ctrl[64 + pi];
    const int e  = pr >> 16;
    const int mt = pr & 0xffff;
    const int n_e = ctrl[e];
    const int base = ctrl[32 + e];
    const int row0 = mt * 128;

    unsigned short* As = &Sh[0][0];
    unsigned short* Bs = &Sh[1][0];

    const int lane = tid & 63, wv = tid >> 6;
    const int wm = wv >> 1, wn = wv & 1;
    const int lr = lane & 15, lq = lane >> 4;

    if (tid < 128) toks[tid] = ltok[e * B_TOK + min(row0 + tid, n_e - 1)];
    __syncthreads();

    const unsigned short* a_src[4];
    const unsigned short* b_src[4];
    #pragma unroll
    for (int c = 0; c < 4; c++) {
        int s = (wv * 4 + c) * 64 + lane;
        int r = s >> 3;
        int kc = (s & 7) ^ (r & 7);
        a_src[c] = xbf + (size_t)toks[r] * DIM + kc * 8;
        b_src[c] = w1t + ((size_t)(e * HID + nt * 128 + r)) * DIM + kc * 8;
    }

    f32x4 acc[4][4];
    #pragma unroll
    for (int m = 0; m < 4; m++)
        #pragma unroll
        for (int n = 0; n < 4; n++) acc[m][n] = (f32x4){0.f, 0.f, 0.f, 0.f};

    for (int kt = 0; kt < DIM; kt += 64) {
        #pragma unroll
        for (int c = 0; c < 4; c++) {
            gl_lds16(a_src[c] + kt, &As[(wv * 4 + c) * 512]);
            gl_lds16(b_src[c] + kt, &Bs[(wv * 4 + c) * 512]);
        }
        __syncthreads();
        #pragma unroll
        for (int kk = 0; kk < 64; kk += 32) {
            bf16x8 af[4], bfr[4];
            #pragma unroll
            for (int i = 0; i < 4; i++) {
                af[i]  = fragRD(As, wm * 64 + i * 16 + lr, kk + lq * 8);
                bfr[i] = fragRD(Bs, wn * 64 + i * 16 + lr, kk + lq * 8);
            }
            #pragma unroll
            for (int i = 0; i < 4; i++)
                #pragma unroll
                for (int j = 0; j < 4; j++)
                    acc[i][j] = __builtin_amdgcn_mfma_f32_16x16x32_bf16(af[i], bfr[j], acc[i][j], 0, 0, 0);
        }
        __syncthreads();
    }

    // epilogue phase 1: bias + relu -> Sh (swizzled 16B-chunk layout, row stride 256B)
    unsigned short* St = &Sh[0][0];
    #pragma unroll
    for (int j = 0; j < 4; j++) {
        int col = wn * 64 + j * 16 + lr;
        float bias = b1[e * HID + nt * 128 + col];
        #pragma unroll
        for (int i = 0; i < 4; i++) {
            #pragma unroll
            for (int q = 0; q < 4; q++) {
                int row = wm * 64 + i * 16 + lq * 4 + q;
                float v = acc[i][j][q] + bias;
                v = v > 0.0f ? v : 0.0f;
                int byte = row * 256 + ((col * 2) ^ ((row & 7) << 4));
                *(unsigned short*)((char*)St + byte) = f2bf(v);
            }
        }
    }
    __syncthreads();
    // epilogue phase 2: coalesced 16B stores (16 threads per 128-short row)
    #pragma unroll
    for (int r8 = 0; r8 < 8; r8++) {
        int idx = r8 * 2048 + tid * 8;
        int row = idx >> 7;
        int colw = idx & 127;
        int pos = row0 + row;
        if (pos < n_e) {
            int byte = row * 256 + ((colw * 2) ^ ((row & 7) << 4));
            ushort8 o = *(const ushort8*)((const char*)St + byte);
            *(ushort8*)(hbuf + (size_t)(base + pos) * HID + nt * 128 + colw) = o;
        }
    }
}

// ---------------- pass 2: yslot[slot] = gate*(H_e @ w2t^T + b2)  tile 128x128 ----------------
// At the m97-structure ceiling (~860 TF): 544 blocks / 768 slots = one generation.
__global__ __launch_bounds__(256, 3) void k_ffn2(
        const unsigned short* __restrict__ hbuf, const unsigned short* __restrict__ w2t,
        const float* __restrict__ b2, const int* __restrict__ ctrl,
        const int* __restrict__ ltok, const float* __restrict__ lgate,
        unsigned short* __restrict__ yslot) {
    const int orig = blockIdx.x;
    const int wgid = (orig & 7) * 72 + (orig >> 3);
    const int pi = wgid >> 2, nt = wgid & 3;
    if (pi >= ctrl[48]) return;
    const int pr = ctrl[64 + pi];
    const int e  = pr >> 16;
    const int mt = pr & 0xffff;
    const int n_e = ctrl[e];
    const int base = ctrl[32 + e];
    const int row0 = mt * 128;

    __shared__ __align__(16) unsigned short Sh[2][128 * 64];
    __shared__ float gts[128];
    unsigned short* As = &Sh[0][0];
    unsigned short* Bs = &Sh[1][0];

    const int tid = threadIdx.x;
    const int lane = tid & 63, wv = tid >> 6;
    const int wm = wv >> 1, wn = wv & 1;
    const int lr = lane & 15, lq = lane >> 4;

    if (tid < 128) {
        int p = min(row0 + tid, n_e - 1);
        gts[tid] = lgate[e * B_TOK + p];
    }
    __syncthreads();

    const unsigned short* a_src[4];
    const unsigned short* b_src[4];
    #pragma unroll
    for (int c = 0; c < 4; c++) {
        int s = (wv * 4 + c) * 64 + lane;
        int r = s >> 3;
        int kc = (s & 7) ^ (r & 7);
        a_src[c] = hbuf + (size_t)(base + min(row0 + r, n_e - 1)) * HID + kc * 8;
        b_src[c] = w2t + ((size_t)(e * DIM + nt * 128 + r)) * HID + kc * 8;
    }

    f32x4 acc[4][4];
    #pragma unroll
    for (int m = 0; m < 4; m++)
        #pragma unroll
        for (int n = 0; n < 4; n++) acc[m][n] = (f32x4){0.f, 0.f, 0.f, 0.f};

    for (int kt = 0; kt < HID; kt += 64) {
        #pragma unroll
        for (int c = 0; c < 4; c++) {
            gl_lds16(a_src[c] + kt, &As[(wv * 4 + c) * 512]);
            gl_lds16(b_src[c] + kt, &Bs[(wv * 4 + c) * 512]);
        }
        __syncthreads();
        #pragma unroll
        for (int kk = 0; kk < 64; kk += 32) {
            bf16x8 af[4], bfr[4];
            #pragma unroll
            for (int i = 0; i < 4; i++) {
                af[i]  = fragRD(As, wm * 64 + i * 16 + lr, kk + lq * 8);
                bfr[i] = fragRD(Bs, wn * 64 + i * 16 + lr, kk + lq * 8);
            }
            #pragma unroll
            for (int i = 0; i < 4; i++)
                #pragma unroll
                for (int j = 0; j < 4; j++)
                    acc[i][j] = __builtin_amdgcn_mfma_f32_16x16x32_bf16(af[i], bfr[j], acc[i][j], 0, 0, 0);
        }
        __syncthreads();
    }

    // epilogue phase 1: bias + gate -> Sh (swizzled, row stride 256B)
    unsigned short* St = &Sh[0][0];
    #pragma unroll
    for (int j = 0; j < 4; j++) {
        int col = wn * 64 + j * 16 + lr;
        float bias = b2[e * DIM + nt * 128 + col];
        #pragma unroll
        for (int i = 0; i < 4; i++) {
            #pragma unroll
            for (int q = 0; q < 4; q++) {
                int row = wm * 64 + i * 16 + lq * 4 + q;
                float v = (acc[i][j][q] + bias) * gts[row];
                int byte = row * 256 + ((col * 2) ^ ((row & 7) << 4));
                *(unsigned short*)((char*)St + byte) = f2bf(v);
            }
        }
    }
    __syncthreads();
    // epilogue phase 2: coalesced 16B stores
    #pragma unroll
    for (int r8 = 0; r8 < 8; r8++) {
        int idx = r8 * 2048 + tid * 8;
        int row = idx >> 7;
        int colw = idx & 127;
        int pos = row0 + row;
        if (pos < n_e) {
            int byte = row * 256 + ((colw * 2) ^ ((row & 7) << 4));
            ushort8 o = *(const ushort8*)((const char*)St + byte);
            *(ushort8*)(yslot + (size_t)(base + pos) * DIM + nt * 128 + colw) = o;
        }
    }
}

// ---------------- kernel 5: y[b] = sum_j yslot[slot_j(b)]  (coalesced, no atomics) ----------------
// 4 tokens/block, 16B loads; grid 1024.
__global__ __launch_bounds__(256) void k_gather(
        const unsigned short* __restrict__ yslot, const int* __restrict__ posmap,
        const int* __restrict__ ctrl, float* __restrict__ y) {
    const int tok = blockIdx.x * 4 + (threadIdx.x >> 6);
    const int c8  = (threadIdx.x & 63) * 8;
    float s[8] = {0.f, 0.f, 0.f, 0.f, 0.f, 0.f, 0.f, 0.f};
    #pragma unroll
    for (int j = 0; j < NSLOT; j++) {
        int pm = posmap[tok * NSLOT + j];
        int e = pm >> 12, p = pm & 4095;
        size_t row = (size_t)(ctrl[32 + e] + p);
        ushort8 v = *(const ushort8*)(yslot + row * DIM + c8);
        #pragma unroll
        for (int q = 0; q < 8; q++) s[q] += bf2f(v[q]);
    }
    float4 o0 = {s[0], s[1], s[2], s[3]};
    float4 o1 = {s[4], s[5], s[6], s[7]};
    *(float4*)(y + (size_t)tok * DIM + c8)     = o0;
    *(float4*)(y + (size_t)tok * DIM + c8 + 4) = o1;
}

// ---------------- host launcher ----------------
extern "C" void kernel_launch(void* const* d_in, const int* in_sizes, int n_in,
                              void* d_out, int out_size, void* d_ws, size_t ws_size,
                              hipStream_t stream) {
    const float* x  = (const float*)d_in[0];
    const float* gx = (const float*)d_in[1];
    const float* wg = (const float*)d_in[2];
    const float* w1 = (const float*)d_in[3];
    const float* b1 = (const float*)d_in[4];
    const float* w2 = (const float*)d_in[5];
    const float* b2 = (const float*)d_in[6];
    float* out = (float*)d_out;

    char* ws = (char*)d_ws;
    float* logits = (float*)(ws + LOGITS_OFF);
    int*   ltok   = (int*)(ws + LTOK_OFF);
    float* lgate  = (float*)(ws + LGATE_OFF);
    int*   ctrl   = (int*)(ws + CTRL_OFF);
    int*   cnt    = ctrl;
    float* imp    = (float*)(ctrl + 16);
    int*   posmap = (int*)(ws + PMAP_OFF);
    unsigned short* xbf   = (unsigned short*)(ws + XBF_OFF);
    unsigned short* w1t   = (unsigned short*)(ws + W1T_OFF);
    unsigned short* w2t   = (unsigned short*)(ws + W2T_OFF);
    unsigned short* hbuf  = (unsigned short*)(ws + H_OFF);
    unsigned short* yslot = (unsigned short*)(ws + YS_OFF);   // aliases w1t (dead after ffn1)

    hipLaunchKernelGGL(k_init, dim3(4096), dim3(256), 0, stream,
                       cnt, imp, x, xbf, w1, w1t, gx, wg, logits);
    hipLaunchKernelGGL(k_route, dim3(B_TOK / 64), dim3(64), 0, stream,
                       logits, cnt, imp, ltok, lgate, posmap);
    hipLaunchKernelGGL(k_prep, dim3(1), dim3(64), 0, stream, ctrl,
                       out + (size_t)B_TOK * DIM);
    hipLaunchKernelGGL(k_ffn1, dim3(3328), dim3(256), 0, stream,
                       xbf, w1t, b1, ctrl, ltok, hbuf, w2, w2t);
    hipLaunchKernelGGL(k_ffn2, dim3(576), dim3(256), 0, stream,
                       hbuf, w2t, b2, ctrl, ltok, lgate, yslot);
    hipLaunchKernelGGL(k_gather, dim3(B_TOK / 4), dim3(256), 0, stream,
                       yslot, posmap, ctrl, out);
}